// Round 1
// baseline (2230.036 us; speedup 1.0000x reference)
//
#include <hip/hip_runtime.h>

// ---------------------------------------------------------------------------
// conv 3x3 VALID + bias + maxpool 2x2 + ReLU, one pooled output per thread
// (used for conv1 where pooled dims are odd: 63x63)
// ---------------------------------------------------------------------------
template<int CIN, int HIN, int WIN, int HP, int WP, int COUT>
__global__ __launch_bounds__(256)
void conv_pool_1(const float* __restrict__ in, const float* __restrict__ wt,
                 const float* __restrict__ bias, float* __restrict__ out)
{
    const int B = 32;
    const size_t total = (size_t)B * COUT * HP * WP;
    size_t idx = (size_t)blockIdx.x * 256 + threadIdx.x;
    if (idx >= total) return;
    int pw = (int)(idx % WP);
    int ph = (int)((idx / WP) % HP);
    int co = (int)((idx / ((size_t)WP * HP)) % COUT);
    int b  = (int)(idx / ((size_t)WP * HP * COUT));

    const float* ip = in + ((size_t)b * CIN) * HIN * WIN + (size_t)(2 * ph) * WIN + 2 * pw;
    const float* wp = wt + (size_t)co * CIN * 9;

    float s00 = 0.f, s01 = 0.f, s10 = 0.f, s11 = 0.f;
    for (int ci = 0; ci < CIN; ++ci) {
        float p[4][4];
#pragma unroll
        for (int r = 0; r < 4; ++r)
#pragma unroll
            for (int c = 0; c < 4; ++c) p[r][c] = ip[r * WIN + c];
        float w[9];
#pragma unroll
        for (int k = 0; k < 9; ++k) w[k] = wp[k];
#pragma unroll
        for (int kh = 0; kh < 3; ++kh)
#pragma unroll
            for (int kw = 0; kw < 3; ++kw) {
                float wv = w[kh * 3 + kw];
                s00 = fmaf(wv, p[kh][kw],       s00);
                s01 = fmaf(wv, p[kh][kw + 1],   s01);
                s10 = fmaf(wv, p[kh + 1][kw],   s10);
                s11 = fmaf(wv, p[kh + 1][kw + 1], s11);
            }
        ip += (size_t)HIN * WIN;
        wp += 9;
    }
    float v = fmaxf(fmaxf(s00, s01), fmaxf(s10, s11)) + bias[co];
    out[idx] = fmaxf(v, 0.f);
}

// ---------------------------------------------------------------------------
// conv 3x3 VALID + bias + maxpool 2x2 + ReLU, 2x2 pooled outputs per thread
// (pooled dims must be even: conv2/3/4)
// ---------------------------------------------------------------------------
template<int CIN, int HIN, int WIN, int HP, int WP, int COUT>
__global__ __launch_bounds__(256)
void conv_pool_2(const float* __restrict__ in, const float* __restrict__ wt,
                 const float* __restrict__ bias, float* __restrict__ out)
{
    const int B = 32;
    const int TH = HP / 2, TW = WP / 2;
    const size_t total = (size_t)B * COUT * TH * TW;
    size_t idx = (size_t)blockIdx.x * 256 + threadIdx.x;
    if (idx >= total) return;
    int tw = (int)(idx % TW);
    int th = (int)((idx / TW) % TH);
    int co = (int)((idx / ((size_t)TW * TH)) % COUT);
    int b  = (int)(idx / ((size_t)TW * TH * COUT));

    const float* ip = in + ((size_t)b * CIN) * HIN * WIN + (size_t)(4 * th) * WIN + 4 * tw;
    const float* wp = wt + (size_t)co * CIN * 9;

    float acc[4][4];
#pragma unroll
    for (int y = 0; y < 4; ++y)
#pragma unroll
        for (int x = 0; x < 4; ++x) acc[y][x] = 0.f;

    for (int ci = 0; ci < CIN; ++ci) {
        float p[6][6];
#pragma unroll
        for (int r = 0; r < 6; ++r)
#pragma unroll
            for (int c = 0; c < 6; ++c) p[r][c] = ip[r * WIN + c];
        float w[9];
#pragma unroll
        for (int k = 0; k < 9; ++k) w[k] = wp[k];
#pragma unroll
        for (int y = 0; y < 4; ++y)
#pragma unroll
            for (int x = 0; x < 4; ++x)
#pragma unroll
                for (int kh = 0; kh < 3; ++kh)
#pragma unroll
                    for (int kw = 0; kw < 3; ++kw)
                        acc[y][x] = fmaf(w[kh * 3 + kw], p[y + kh][x + kw], acc[y][x]);
        ip += (size_t)HIN * WIN;
        wp += 9;
    }
    float bz = bias[co];
#pragma unroll
    for (int dy = 0; dy < 2; ++dy)
#pragma unroll
        for (int dx = 0; dx < 2; ++dx) {
            float v = fmaxf(fmaxf(acc[2 * dy][2 * dx],     acc[2 * dy][2 * dx + 1]),
                            fmaxf(acc[2 * dy + 1][2 * dx], acc[2 * dy + 1][2 * dx + 1])) + bz;
            out[(((size_t)b * COUT + co) * HP + (2 * th + dy)) * WP + (2 * tw + dx)] = fmaxf(v, 0.f);
        }
}

// ---------------------------------------------------------------------------
// Y[b, o0 + j] = act( X[b,:] . W[o0+j,:] + bias[o0+j] ), j = 0,1 ; B = 32
// grid = N/2 blocks, 256 threads
// ---------------------------------------------------------------------------
__global__ __launch_bounds__(256)
void fc_two(const float* __restrict__ X, const float* __restrict__ W,
            const float* __restrict__ bias, float* __restrict__ Y,
            int K, int N, int act)
{
    int o0 = blockIdx.x * 2;
    int tid = threadIdx.x;
    const float* w0 = W + (size_t)o0 * K;
    const float* w1 = w0 + K;
    float a0[32], a1[32];
#pragma unroll
    for (int b = 0; b < 32; ++b) { a0[b] = 0.f; a1[b] = 0.f; }

    for (int k = tid; k < K; k += 256) {
        float wv0 = w0[k], wv1 = w1[k];
#pragma unroll
        for (int b = 0; b < 32; ++b) {
            float xv = X[(size_t)b * K + k];
            a0[b] = fmaf(wv0, xv, a0[b]);
            a1[b] = fmaf(wv1, xv, a1[b]);
        }
    }
    __shared__ float part[2][4][32];
    int lane = tid & 63, wv = tid >> 6;
#pragma unroll
    for (int b = 0; b < 32; ++b) {
        float s0 = a0[b], s1 = a1[b];
#pragma unroll
        for (int off = 32; off >= 1; off >>= 1) {
            s0 += __shfl_down(s0, off);
            s1 += __shfl_down(s1, off);
        }
        if (lane == 0) { part[0][wv][b] = s0; part[1][wv][b] = s1; }
    }
    __syncthreads();
    if (tid < 64) {
        int j = tid >> 5, b = tid & 31;
        float s = part[j][0][b] + part[j][1][b] + part[j][2][b] + part[j][3][b] + bias[o0 + j];
        if (act) s = tanhf(s);
        Y[(size_t)b * N + o0 + j] = s;
    }
}

// ---------------------------------------------------------------------------
// softmax over 10 logits -> ratio (output), then seg_limit rebalance
// 1 block, 64 threads, lane b < 32
// ---------------------------------------------------------------------------
__global__ __launch_bounds__(64)
void post_kernel(const float* __restrict__ logits, float* __restrict__ ratio_out,
                 float* __restrict__ sl_out)
{
    int b = threadIdx.x;
    if (b >= 32) return;
    float lg[10];
#pragma unroll
    for (int j = 0; j < 10; ++j) lg[j] = logits[b * 10 + j];
    float mx = lg[0];
#pragma unroll
    for (int j = 1; j < 10; ++j) mx = fmaxf(mx, lg[j]);
    float e[10]; float ssum = 0.f;
#pragma unroll
    for (int j = 0; j < 10; ++j) { e[j] = expf(lg[j] - mx); ssum += e[j]; }
    float sl[10];
#pragma unroll
    for (int j = 0; j < 10; ++j) {
        float r = e[j] / ssum;
        ratio_out[b * 10 + j] = r;
        sl[j] = ceilf(r * 200.f);
    }
#pragma unroll
    for (int it = 0; it < 10; ++it) {
        float s = 0.f, mx2 = sl[0];
#pragma unroll
        for (int j = 0; j < 10; ++j) { s += sl[j]; mx2 = fmaxf(mx2, sl[j]); }
        float over = (s != 200.f) ? 1.f : 0.f;
        float reduced = 1.f;
#pragma unroll
        for (int j = 0; j < 10; ++j) {
            float mult = (sl[j] == mx2) ? 1.f : 0.f;
            sl[j] -= mult * reduced * over;
            reduced = fmaxf(reduced - mult, 0.f);
        }
    }
#pragma unroll
    for (int j = 0; j < 10; ++j) sl_out[b * 10 + j] = sl[j];
}

// ---------------------------------------------------------------------------
// trajectory assembly: grid 32 (batch), 256 threads (200 active points)
// ---------------------------------------------------------------------------
__global__ __launch_bounds__(256)
void traj_kernel(const float* __restrict__ base, const float* __restrict__ ipos,
                 const float* __restrict__ sm, float* __restrict__ out_traj,
                 float* __restrict__ out_starts)
{
    int b = blockIdx.x;
    int j = threadIdx.x;
    float bx0 = base[0], by0 = base[1];
    float bxL = base[398], byL = base[399];
    float bx = 0.f, by = 0.f;
    if (j < 200) { bx = base[2 * j]; by = base[2 * j + 1]; }
    float curx = ipos[b * 2 + 0], cury = ipos[b * 2 + 1];
    if (j == 0) { out_starts[b * 22 + 0] = curx; out_starts[b * 22 + 1] = cury; }
#pragma unroll
    for (int i = 0; i < 10; ++i) {
        float sx  = sm[b * 30 + i * 3 + 0];
        float sy  = sm[b * 30 + i * 3 + 1];
        float rot = tanhf(sm[b * 30 + i * 3 + 2]) * 3.14f;
        float c = cosf(rot), s = sinf(rot);
        float cx = bx0 * sx, cy = by0 * sy;
        if (j < 200) {
            float px = bx * sx, py = by * sy;
            float rx = c * (px - cx) - s * (py - cy) + cx;
            float ry = s * (px - cx) + c * (py - cy) + cy;
            size_t o = ((size_t)b * 2000 + i * 200 + j) * 2;
            out_traj[o + 0] = curx + rx;
            out_traj[o + 1] = cury + ry;
        }
        float pxL = bxL * sx, pyL = byL * sy;
        float exL = c * (pxL - cx) - s * (pyL - cy) + cx;
        float eyL = s * (pxL - cx) + c * (pyL - cy) + cy;
        curx += exL; cury += eyL;
        if (j == 0) {
            out_starts[b * 22 + (i + 1) * 2 + 0] = curx;
            out_starts[b * 22 + (i + 1) * 2 + 1] = cury;
        }
    }
}

// ---------------------------------------------------------------------------
// sampler: event-jump exact reimplementation of the reference scan.
// For i>=2 force==true (seg_ids[i] != i-1 for all i>=2), so di = new_di each
// step; state only changes on a fire or segment boundary -> jump between
// events. 1 block, 64 threads, lane = batch.
// ---------------------------------------------------------------------------
__global__ __launch_bounds__(64)
void sample_kernel(const float* __restrict__ sl_in, const float* __restrict__ traj,
                   float* __restrict__ samp_out)
{
    __shared__ unsigned int maskb[32][63];
    __shared__ float ssl[32][10];
    int tid = threadIdx.x;
    for (int t = tid; t < 32 * 63; t += 64) ((unsigned int*)maskb)[t] = 0u;
    for (int t = tid; t < 32 * 10; t += 64) ((float*)ssl)[t] = sl_in[t];
    __syncthreads();
    if (tid >= 32) return;
    int b = tid;
    const float* tb = traj + (size_t)b * 4000;
    float* sp = samp_out + (size_t)b * 400;
    int out_n = 0;
    float last = 0.f, ntot = 0.f;
    float lim0 = ssl[b][0];
    float di = floorf(199.f / lim0);
    float ct0 = 0.f;
    // i = 0 (force false; new_di == di -> no change)
    if ((ntot < 200.f) && (ct0 < lim0) && (0.f - last == di)) {
        // last_idx = max(0, 0*1) = 0
        ntot += 1.f; ct0 += 1.f;
        maskb[b][0] |= 1u;
        sp[out_n * 2] = tb[0]; sp[out_n * 2 + 1] = tb[1]; ++out_n;
    }
    // i = 1 (force false; di updated only if di < new_di)
    {
        float ndi = floorf((199.f - last) / (lim0 - ct0));
        if (di < ndi) di = ndi;
        if ((ntot < 200.f) && (ct0 < lim0) && (1.f - last == di)) {
            last = 1.f; ntot += 1.f; ct0 += 1.f;
            maskb[b][0] |= 2u;
            sp[out_n * 2] = tb[2]; sp[out_n * 2 + 1] = tb[3]; ++out_n;
        }
    }
    // i >= 2: event jumps
    for (int seg = 0; seg < 10; ++seg) {
        float lim = ssl[b][seg];
        float ct = (seg == 0) ? ct0 : 0.f;
        float segbase = 200.f * seg;
        float segend = segbase + 199.f;
        float pos = (seg == 0) ? 2.f : segbase;
        float ndi = floorf((199.f - (last - segbase)) / (lim - ct));
        while ((ntot < 200.f) && (ct < lim)) {
            float fi = last + ndi;
            if (!(fi >= pos && fi <= segend)) break;
            int i = (int)fi;
            last = fi; ntot += 1.f; ct += 1.f;
            maskb[b][i >> 5] |= (1u << (i & 31));
            sp[out_n * 2] = tb[2 * i]; sp[out_n * 2 + 1] = tb[2 * i + 1]; ++out_n;
            pos = fi + 1.f;
            ndi = floorf((199.f - (last - segbase)) / (lim - ct));
        }
    }
    // pad with unfired indices in ascending order (== stable argsort tail)
    for (int i = 0; i < 2000 && out_n < 200; ++i) {
        if (!((maskb[b][i >> 5] >> (i & 31)) & 1u)) {
            sp[out_n * 2] = tb[2 * i]; sp[out_n * 2 + 1] = tb[2 * i + 1]; ++out_n;
        }
    }
}

// ---------------------------------------------------------------------------
extern "C" void kernel_launch(void* const* d_in, const int* in_sizes, int n_in,
                              void* d_out, int out_size, void* d_ws, size_t ws_size,
                              hipStream_t stream)
{
    const float* x    = (const float*)d_in[0];
    const float* w1   = (const float*)d_in[1];
    const float* b1   = (const float*)d_in[2];
    const float* w2   = (const float*)d_in[3];
    const float* b2   = (const float*)d_in[4];
    const float* w3   = (const float*)d_in[5];
    const float* b3   = (const float*)d_in[6];
    const float* w4   = (const float*)d_in[7];
    const float* b4   = (const float*)d_in[8];
    const float* fcw1 = (const float*)d_in[9];
    const float* fcb1 = (const float*)d_in[10];
    const float* fcw2 = (const float*)d_in[11];
    const float* fcb2 = (const float*)d_in[12];
    const float* wi   = (const float*)d_in[13];
    const float* bi   = (const float*)d_in[14];
    const float* wsw  = (const float*)d_in[15];
    const float* bs   = (const float*)d_in[16];
    const float* wr   = (const float*)d_in[17];
    const float* br   = (const float*)d_in[18];
    const float* base = (const float*)d_in[19];

    float* out = (float*)d_out;
    float* ws  = (float*)d_ws;

    // ws layout (floats), with liveness-based reuse; peak = 11,814,912 floats
    float* p1   = ws + 0;        // 32x64x63x63   (8,128,512)
    float* p2   = ws + 8128512;  // 32x128x30x30  (3,686,400)
    float* p3   = ws + 0;        // 32x256x14x14  (reuses p1)
    float* feat = ws + 8128512;  // 32x512x6x6    (reuses p2)
    float* z1   = ws + 0;        // 32x2048       (reuses p3)
    float* z2   = ws + 65536;    // 32x2048
    float* ipos = ws + 131072;   // 32x2
    float* smod = ws + 131136;   // 32x30
    float* rlog = ws + 132096;   // 32x10
    float* slim = ws + 132416;   // 32x10

    float* out_samp   = out;            // 32*200*2 = 12800
    float* out_starts = out + 12800;    // 32*11*2  = 704
    float* out_ratio  = out + 13504;    // 32*10    = 320
    float* out_traj   = out + 13824;    // 32*2000*2 = 128000

    conv_pool_1<3, 128, 128, 63, 63, 64><<<31752, 256, 0, stream>>>(x, w1, b1, p1);
    conv_pool_2<64, 63, 63, 30, 30, 128><<<3600, 256, 0, stream>>>(p1, w2, b2, p2);
    conv_pool_2<128, 30, 30, 14, 14, 256><<<1568, 256, 0, stream>>>(p2, w3, b3, p3);
    conv_pool_2<256, 14, 14, 6, 6, 512><<<576, 256, 0, stream>>>(p3, w4, b4, feat);

    fc_two<<<1024, 256, 0, stream>>>(feat, fcw1, fcb1, z1, 18432, 2048, 1);
    fc_two<<<1024, 256, 0, stream>>>(z1, fcw2, fcb2, z2, 2048, 2048, 0);

    fc_two<<<1, 256, 0, stream>>>(z2, wi, bi, ipos, 2048, 2, 0);
    fc_two<<<15, 256, 0, stream>>>(z2, wsw, bs, smod, 2048, 30, 0);
    fc_two<<<5, 256, 0, stream>>>(z2, wr, br, rlog, 2048, 10, 0);

    post_kernel<<<1, 64, 0, stream>>>(rlog, out_ratio, slim);
    traj_kernel<<<32, 256, 0, stream>>>(base, ipos, smod, out_traj, out_starts);
    sample_kernel<<<1, 64, 0, stream>>>(slim, out_traj, out_samp);
}

// Round 2
// 1291.423 us; speedup vs baseline: 1.7268x; 1.7268x over previous
//
#include <hip/hip_runtime.h>

// ===========================================================================
// conv1: 3->64, 128x128 in, pooled 63x63. Block = (b, co_grp of 8, 4x4 tile
// of 16x16 pooled px). Stage all 3 ci patch tiles once into LDS.
// ===========================================================================
__global__ __launch_bounds__(256)
void conv1_lds(const float* __restrict__ in, const float* __restrict__ wt,
               const float* __restrict__ bias, float* __restrict__ out)
{
    __shared__ float sh[3][34][34];
    int bx = blockIdx.x;
    int tile = bx & 15;
    int cg   = (bx >> 4) & 7;
    int b    = bx >> 7;
    int tr = tile >> 2, tc = tile & 3;
    int tid = threadIdx.x;
    int ty = tid >> 4, tx = tid & 15;
    int R0 = 32 * tr, C0 = 32 * tc;

    // stage 3 x 34 x 34 patch (clamped at image edge; clamped region unused)
    for (int t = tid; t < 3 * 34 * 34; t += 256) {
        int ci = t / 1156;
        int rem = t - ci * 1156;
        int rr = rem / 34, cc = rem - rr * 34;
        int gr = R0 + rr; if (gr > 127) gr = 127;
        int gc = C0 + cc; if (gc > 127) gc = 127;
        sh[ci][rr][cc] = in[(((size_t)b * 3 + ci) * 128 + gr) * 128 + gc];
    }
    __syncthreads();

    float acc[8][2][2] = {};
    int co0 = cg * 8;
#pragma unroll
    for (int ci = 0; ci < 3; ++ci) {
        float p[4][4];
#pragma unroll
        for (int r = 0; r < 4; ++r) {
            const float2* pr = reinterpret_cast<const float2*>(&sh[ci][2 * ty + r][2 * tx]);
            float2 a = pr[0], c2 = pr[1];
            p[r][0] = a.x; p[r][1] = a.y; p[r][2] = c2.x; p[r][3] = c2.y;
        }
#pragma unroll
        for (int j = 0; j < 8; ++j) {
            const float* wj = wt + ((size_t)(co0 + j) * 3 + ci) * 9;
#pragma unroll
            for (int kh = 0; kh < 3; ++kh)
#pragma unroll
                for (int kw = 0; kw < 3; ++kw) {
                    float wv = wj[kh * 3 + kw];
#pragma unroll
                    for (int dy = 0; dy < 2; ++dy)
#pragma unroll
                        for (int dx = 0; dx < 2; ++dx)
                            acc[j][dy][dx] = fmaf(wv, p[dy + kh][dx + kw], acc[j][dy][dx]);
                }
        }
    }
    int py = 16 * tr + ty, px = 16 * tc + tx;
    if (py < 63 && px < 63) {
#pragma unroll
        for (int j = 0; j < 8; ++j) {
            float v = fmaxf(fmaxf(acc[j][0][0], acc[j][0][1]),
                            fmaxf(acc[j][1][0], acc[j][1][1])) + bias[co0 + j];
            out[(((size_t)b * 64 + co0 + j) * 63 + py) * 63 + px] = fmaxf(v, 0.f);
        }
    }
}

// ===========================================================================
// conv2/conv3: LDS-staged, 8 co per thread, 1 pooled px per thread.
// Block = (b, co_grp, spatial tile of TH x TW pooled px).
// ===========================================================================
template<int CIN, int HIN, int WIN, int PH, int PW, int COUT,
         int TH, int TW, int CI_BLK, int TILES_H, int TILES_W>
__global__ __launch_bounds__(256)
void conv_lds(const float* __restrict__ in, const float* __restrict__ wt,
              const float* __restrict__ bias, float* __restrict__ out)
{
    constexpr int RH = 2 * TH + 2;
    constexpr int CW = 2 * TW + 2;
    constexpr int CWp = (CW % 32 == 0) ? CW + 2 : CW;
    __shared__ float sh[CI_BLK][RH][CWp];

    int bx = blockIdx.x;
    constexpr int NTILES = TILES_H * TILES_W;
    int tile = bx % NTILES;
    int cg = (bx / NTILES) % (COUT / 8);
    int b  = bx / (NTILES * (COUT / 8));
    int thi = tile / TILES_W, twi = tile % TILES_W;
    int R0 = 2 * TH * thi, C0 = 2 * TW * twi;

    int tid = threadIdx.x;
    int ty = tid / TW, tx = tid - ty * TW;
    bool active = (tid < TH * TW);

    float acc[8][2][2] = {};
    int co0 = cg * 8;

    for (int ci0 = 0; ci0 < CIN; ci0 += CI_BLK) {
        __syncthreads();
        for (int t = tid; t < CI_BLK * RH * CW; t += 256) {
            int ci = t / (RH * CW);
            int rem = t - ci * (RH * CW);
            int rr = rem / CW, cc = rem - rr * CW;
            sh[ci][rr][cc] = in[(((size_t)b * CIN + ci0 + ci) * HIN + (R0 + rr)) * WIN + (C0 + cc)];
        }
        __syncthreads();
        if (active) {
#pragma unroll
            for (int ci = 0; ci < CI_BLK; ++ci) {
                float p[4][4];
#pragma unroll
                for (int r = 0; r < 4; ++r) {
                    const float2* pr = reinterpret_cast<const float2*>(&sh[ci][2 * ty + r][2 * tx]);
                    float2 a = pr[0], c2 = pr[1];
                    p[r][0] = a.x; p[r][1] = a.y; p[r][2] = c2.x; p[r][3] = c2.y;
                }
#pragma unroll
                for (int j = 0; j < 8; ++j) {
                    const float* wj = wt + ((size_t)(co0 + j) * CIN + (ci0 + ci)) * 9;
#pragma unroll
                    for (int kh = 0; kh < 3; ++kh)
#pragma unroll
                        for (int kw = 0; kw < 3; ++kw) {
                            float wv = wj[kh * 3 + kw];
#pragma unroll
                            for (int dy = 0; dy < 2; ++dy)
#pragma unroll
                                for (int dx = 0; dx < 2; ++dx)
                                    acc[j][dy][dx] = fmaf(wv, p[dy + kh][dx + kw], acc[j][dy][dx]);
                        }
                }
            }
        }
    }
    if (active) {
        int py = TH * thi + ty, px = TW * twi + tx;
        if (py < PH && px < PW) {
#pragma unroll
            for (int j = 0; j < 8; ++j) {
                float v = fmaxf(fmaxf(acc[j][0][0], acc[j][0][1]),
                                fmaxf(acc[j][1][0], acc[j][1][1])) + bias[co0 + j];
                out[(((size_t)b * COUT + co0 + j) * PH + py) * PW + px] = fmaxf(v, 0.f);
            }
        }
    }
}

// ===========================================================================
// conv4: 256->512, 14x14 in, pooled 6x6. Block = (b, co_grp of 32),
// 128 threads: lane = (co_local = tid>>2, quad = tid&3 -> 6x6 conv px).
// Input chunk AND weight chunk staged in LDS.
// ===========================================================================
__global__ __launch_bounds__(128)
void conv4_lds(const float* __restrict__ in, const float* __restrict__ wt,
               const float* __restrict__ bias, float* __restrict__ out)
{
    __shared__ float in_sh[16][14][16];
    __shared__ float w_sh[32][145];   // [co_local][ci*9+k], pad 145 -> banks 17*co mod 32 (conflict-free)

    int bx = blockIdx.x;
    int cg = bx & 15;
    int b  = bx >> 4;
    int tid = threadIdx.x;
    int co_local = tid >> 2;
    int sub = tid & 3;
    int qr = 6 * (sub >> 1), qc = 6 * (sub & 1);
    int co = cg * 32 + co_local;

    float acc[6][6] = {};

    for (int ci0 = 0; ci0 < 256; ci0 += 16) {
        __syncthreads();
        for (int t = tid; t < 16 * 196; t += 128) {
            int ci = t / 196;
            int rem = t - ci * 196;
            int rr = rem / 14, cc = rem - rr * 14;
            in_sh[ci][rr][cc] = in[(((size_t)b * 256 + ci0 + ci) * 14 + rr) * 14 + cc];
        }
        for (int t = tid; t < 32 * 144; t += 128) {
            int c = t / 144, q = t - c * 144;
            w_sh[c][q] = wt[(size_t)(cg * 32 + c) * 2304 + ci0 * 9 + q];
        }
        __syncthreads();
#pragma unroll 4
        for (int ci = 0; ci < 16; ++ci) {
            float p[8][8];
#pragma unroll
            for (int r = 0; r < 8; ++r) {
                const float2* pr = reinterpret_cast<const float2*>(&in_sh[ci][qr + r][qc]);
                float2 a0 = pr[0], a1 = pr[1], a2 = pr[2], a3 = pr[3];
                p[r][0] = a0.x; p[r][1] = a0.y; p[r][2] = a1.x; p[r][3] = a1.y;
                p[r][4] = a2.x; p[r][5] = a2.y; p[r][6] = a3.x; p[r][7] = a3.y;
            }
#pragma unroll
            for (int kh = 0; kh < 3; ++kh)
#pragma unroll
                for (int kw = 0; kw < 3; ++kw) {
                    float wv = w_sh[co_local][ci * 9 + kh * 3 + kw];
#pragma unroll
                    for (int y = 0; y < 6; ++y)
#pragma unroll
                        for (int x = 0; x < 6; ++x)
                            acc[y][x] = fmaf(wv, p[y + kh][x + kw], acc[y][x]);
                }
        }
    }
    float bz = bias[co];
#pragma unroll
    for (int dy = 0; dy < 3; ++dy)
#pragma unroll
        for (int dx = 0; dx < 3; ++dx) {
            float v = fmaxf(fmaxf(acc[2 * dy][2 * dx],     acc[2 * dy][2 * dx + 1]),
                            fmaxf(acc[2 * dy + 1][2 * dx], acc[2 * dy + 1][2 * dx + 1])) + bz;
            int py = qr / 2 + dy, px = qc / 2 + dx;
            out[(((size_t)b * 512 + co) * 6 + py) * 6 + px] = fmaxf(v, 0.f);
        }
}

// ---------------------------------------------------------------------------
// Y[b, o0 + j] = act( X[b,:] . W[o0+j,:] + bias[o0+j] ), j = 0,1 ; B = 32
// ---------------------------------------------------------------------------
__global__ __launch_bounds__(256)
void fc_two(const float* __restrict__ X, const float* __restrict__ W,
            const float* __restrict__ bias, float* __restrict__ Y,
            int K, int N, int act)
{
    int o0 = blockIdx.x * 2;
    int tid = threadIdx.x;
    const float* w0 = W + (size_t)o0 * K;
    const float* w1 = w0 + K;
    float a0[32], a1[32];
#pragma unroll
    for (int b = 0; b < 32; ++b) { a0[b] = 0.f; a1[b] = 0.f; }

    for (int k = tid; k < K; k += 256) {
        float wv0 = w0[k], wv1 = w1[k];
#pragma unroll
        for (int b = 0; b < 32; ++b) {
            float xv = X[(size_t)b * K + k];
            a0[b] = fmaf(wv0, xv, a0[b]);
            a1[b] = fmaf(wv1, xv, a1[b]);
        }
    }
    __shared__ float part[2][4][32];
    int lane = tid & 63, wv = tid >> 6;
#pragma unroll
    for (int b = 0; b < 32; ++b) {
        float s0 = a0[b], s1 = a1[b];
#pragma unroll
        for (int off = 32; off >= 1; off >>= 1) {
            s0 += __shfl_down(s0, off);
            s1 += __shfl_down(s1, off);
        }
        if (lane == 0) { part[0][wv][b] = s0; part[1][wv][b] = s1; }
    }
    __syncthreads();
    if (tid < 64) {
        int j = tid >> 5, b = tid & 31;
        float s = part[j][0][b] + part[j][1][b] + part[j][2][b] + part[j][3][b] + bias[o0 + j];
        if (act) s = tanhf(s);
        Y[(size_t)b * N + o0 + j] = s;
    }
}

// ---------------------------------------------------------------------------
// softmax over 10 logits -> ratio (output), then seg_limit rebalance
// ---------------------------------------------------------------------------
__global__ __launch_bounds__(64)
void post_kernel(const float* __restrict__ logits, float* __restrict__ ratio_out,
                 float* __restrict__ sl_out)
{
    int b = threadIdx.x;
    if (b >= 32) return;
    float lg[10];
#pragma unroll
    for (int j = 0; j < 10; ++j) lg[j] = logits[b * 10 + j];
    float mx = lg[0];
#pragma unroll
    for (int j = 1; j < 10; ++j) mx = fmaxf(mx, lg[j]);
    float e[10]; float ssum = 0.f;
#pragma unroll
    for (int j = 0; j < 10; ++j) { e[j] = expf(lg[j] - mx); ssum += e[j]; }
    float sl[10];
#pragma unroll
    for (int j = 0; j < 10; ++j) {
        float r = e[j] / ssum;
        ratio_out[b * 10 + j] = r;
        sl[j] = ceilf(r * 200.f);
    }
#pragma unroll
    for (int it = 0; it < 10; ++it) {
        float s = 0.f, mx2 = sl[0];
#pragma unroll
        for (int j = 0; j < 10; ++j) { s += sl[j]; mx2 = fmaxf(mx2, sl[j]); }
        float over = (s != 200.f) ? 1.f : 0.f;
        float reduced = 1.f;
#pragma unroll
        for (int j = 0; j < 10; ++j) {
            float mult = (sl[j] == mx2) ? 1.f : 0.f;
            sl[j] -= mult * reduced * over;
            reduced = fmaxf(reduced - mult, 0.f);
        }
    }
#pragma unroll
    for (int j = 0; j < 10; ++j) sl_out[b * 10 + j] = sl[j];
}

// ---------------------------------------------------------------------------
// trajectory assembly: grid 32 (batch), 256 threads (200 active points)
// ---------------------------------------------------------------------------
__global__ __launch_bounds__(256)
void traj_kernel(const float* __restrict__ base, const float* __restrict__ ipos,
                 const float* __restrict__ sm, float* __restrict__ out_traj,
                 float* __restrict__ out_starts)
{
    int b = blockIdx.x;
    int j = threadIdx.x;
    float bx0 = base[0], by0 = base[1];
    float bxL = base[398], byL = base[399];
    float bx = 0.f, by = 0.f;
    if (j < 200) { bx = base[2 * j]; by = base[2 * j + 1]; }
    float curx = ipos[b * 2 + 0], cury = ipos[b * 2 + 1];
    if (j == 0) { out_starts[b * 22 + 0] = curx; out_starts[b * 22 + 1] = cury; }
#pragma unroll
    for (int i = 0; i < 10; ++i) {
        float sx  = sm[b * 30 + i * 3 + 0];
        float sy  = sm[b * 30 + i * 3 + 1];
        float rot = tanhf(sm[b * 30 + i * 3 + 2]) * 3.14f;
        float c = cosf(rot), s = sinf(rot);
        float cx = bx0 * sx, cy = by0 * sy;
        if (j < 200) {
            float px = bx * sx, py = by * sy;
            float rx = c * (px - cx) - s * (py - cy) + cx;
            float ry = s * (px - cx) + c * (py - cy) + cy;
            size_t o = ((size_t)b * 2000 + i * 200 + j) * 2;
            out_traj[o + 0] = curx + rx;
            out_traj[o + 1] = cury + ry;
        }
        float pxL = bxL * sx, pyL = byL * sy;
        float exL = c * (pxL - cx) - s * (pyL - cy) + cx;
        float eyL = s * (pxL - cx) + c * (pyL - cy) + cy;
        curx += exL; cury += eyL;
        if (j == 0) {
            out_starts[b * 22 + (i + 1) * 2 + 0] = curx;
            out_starts[b * 22 + (i + 1) * 2 + 1] = cury;
        }
    }
}

// ---------------------------------------------------------------------------
// sampler: event-jump exact reimplementation of the reference scan.
// ---------------------------------------------------------------------------
__global__ __launch_bounds__(64)
void sample_kernel(const float* __restrict__ sl_in, const float* __restrict__ traj,
                   float* __restrict__ samp_out)
{
    __shared__ unsigned int maskb[32][63];
    __shared__ float ssl[32][10];
    int tid = threadIdx.x;
    for (int t = tid; t < 32 * 63; t += 64) ((unsigned int*)maskb)[t] = 0u;
    for (int t = tid; t < 32 * 10; t += 64) ((float*)ssl)[t] = sl_in[t];
    __syncthreads();
    if (tid >= 32) return;
    int b = tid;
    const float* tb = traj + (size_t)b * 4000;
    float* sp = samp_out + (size_t)b * 400;
    int out_n = 0;
    float last = 0.f, ntot = 0.f;
    float lim0 = ssl[b][0];
    float di = floorf(199.f / lim0);
    float ct0 = 0.f;
    if ((ntot < 200.f) && (ct0 < lim0) && (0.f - last == di)) {
        ntot += 1.f; ct0 += 1.f;
        maskb[b][0] |= 1u;
        sp[out_n * 2] = tb[0]; sp[out_n * 2 + 1] = tb[1]; ++out_n;
    }
    {
        float ndi = floorf((199.f - last) / (lim0 - ct0));
        if (di < ndi) di = ndi;
        if ((ntot < 200.f) && (ct0 < lim0) && (1.f - last == di)) {
            last = 1.f; ntot += 1.f; ct0 += 1.f;
            maskb[b][0] |= 2u;
            sp[out_n * 2] = tb[2]; sp[out_n * 2 + 1] = tb[3]; ++out_n;
        }
    }
    for (int seg = 0; seg < 10; ++seg) {
        float lim = ssl[b][seg];
        float ct = (seg == 0) ? ct0 : 0.f;
        float segbase = 200.f * seg;
        float segend = segbase + 199.f;
        float pos = (seg == 0) ? 2.f : segbase;
        float ndi = floorf((199.f - (last - segbase)) / (lim - ct));
        while ((ntot < 200.f) && (ct < lim)) {
            float fi = last + ndi;
            if (!(fi >= pos && fi <= segend)) break;
            int i = (int)fi;
            last = fi; ntot += 1.f; ct += 1.f;
            maskb[b][i >> 5] |= (1u << (i & 31));
            sp[out_n * 2] = tb[2 * i]; sp[out_n * 2 + 1] = tb[2 * i + 1]; ++out_n;
            pos = fi + 1.f;
            ndi = floorf((199.f - (last - segbase)) / (lim - ct));
        }
    }
    for (int i = 0; i < 2000 && out_n < 200; ++i) {
        if (!((maskb[b][i >> 5] >> (i & 31)) & 1u)) {
            sp[out_n * 2] = tb[2 * i]; sp[out_n * 2 + 1] = tb[2 * i + 1]; ++out_n;
        }
    }
}

// ---------------------------------------------------------------------------
extern "C" void kernel_launch(void* const* d_in, const int* in_sizes, int n_in,
                              void* d_out, int out_size, void* d_ws, size_t ws_size,
                              hipStream_t stream)
{
    const float* x    = (const float*)d_in[0];
    const float* w1   = (const float*)d_in[1];
    const float* b1   = (const float*)d_in[2];
    const float* w2   = (const float*)d_in[3];
    const float* b2   = (const float*)d_in[4];
    const float* w3   = (const float*)d_in[5];
    const float* b3   = (const float*)d_in[6];
    const float* w4   = (const float*)d_in[7];
    const float* b4   = (const float*)d_in[8];
    const float* fcw1 = (const float*)d_in[9];
    const float* fcb1 = (const float*)d_in[10];
    const float* fcw2 = (const float*)d_in[11];
    const float* fcb2 = (const float*)d_in[12];
    const float* wi   = (const float*)d_in[13];
    const float* bi   = (const float*)d_in[14];
    const float* wsw  = (const float*)d_in[15];
    const float* bs   = (const float*)d_in[16];
    const float* wr   = (const float*)d_in[17];
    const float* br   = (const float*)d_in[18];
    const float* base = (const float*)d_in[19];

    float* out = (float*)d_out;
    float* ws  = (float*)d_ws;

    float* p1   = ws + 0;        // 32x64x63x63   (8,128,512)
    float* p2   = ws + 8128512;  // 32x128x30x30  (3,686,400)
    float* p3   = ws + 0;        // 32x256x14x14  (reuses p1)
    float* feat = ws + 8128512;  // 32x512x6x6    (reuses p2)
    float* z1   = ws + 0;        // 32x2048       (reuses p3)
    float* z2   = ws + 65536;    // 32x2048
    float* ipos = ws + 131072;   // 32x2
    float* smod = ws + 131136;   // 32x30
    float* rlog = ws + 132096;   // 32x10
    float* slim = ws + 132416;   // 32x10

    float* out_samp   = out;            // 32*200*2 = 12800
    float* out_starts = out + 12800;    // 32*11*2  = 704
    float* out_ratio  = out + 13504;    // 32*10    = 320
    float* out_traj   = out + 13824;    // 32*2000*2 = 128000

    conv1_lds<<<4096, 256, 0, stream>>>(x, w1, b1, p1);
    conv_lds<64, 63, 63, 30, 30, 128, 15, 15, 4, 2, 2>
        <<<2048, 256, 0, stream>>>(p1, w2, b2, p2);
    conv_lds<128, 30, 30, 14, 14, 256, 14, 14, 4, 1, 1>
        <<<1024, 256, 0, stream>>>(p2, w3, b3, p3);
    conv4_lds<<<512, 128, 0, stream>>>(p3, w4, b4, feat);

    fc_two<<<1024, 256, 0, stream>>>(feat, fcw1, fcb1, z1, 18432, 2048, 1);
    fc_two<<<1024, 256, 0, stream>>>(z1, fcw2, fcb2, z2, 2048, 2048, 0);

    fc_two<<<1, 256, 0, stream>>>(z2, wi, bi, ipos, 2048, 2, 0);
    fc_two<<<15, 256, 0, stream>>>(z2, wsw, bs, smod, 2048, 30, 0);
    fc_two<<<5, 256, 0, stream>>>(z2, wr, br, rlog, 2048, 10, 0);

    post_kernel<<<1, 64, 0, stream>>>(rlog, out_ratio, slim);
    traj_kernel<<<32, 256, 0, stream>>>(base, ipos, smod, out_traj, out_starts);
    sample_kernel<<<1, 64, 0, stream>>>(slim, out_traj, out_samp);
}

// Round 3
// 1229.994 us; speedup vs baseline: 1.8130x; 1.0499x over previous
//
#include <hip/hip_runtime.h>

// ===========================================================================
// conv1: 3->64, 128x128 in, pooled 63x63. Block = (b, co_grp of 8, 4x4 tile
// of 16x16 pooled px). Stage all 3 ci patch tiles once into LDS.
// ===========================================================================
__global__ __launch_bounds__(256)
void conv1_lds(const float* __restrict__ in, const float* __restrict__ wt,
               const float* __restrict__ bias, float* __restrict__ out)
{
    __shared__ float sh[3][34][34];
    int bx = blockIdx.x;
    int tile = bx & 15;
    int cg   = (bx >> 4) & 7;
    int b    = bx >> 7;
    int tr = tile >> 2, tc = tile & 3;
    int tid = threadIdx.x;
    int ty = tid >> 4, tx = tid & 15;
    int R0 = 32 * tr, C0 = 32 * tc;

    for (int t = tid; t < 3 * 34 * 34; t += 256) {
        int ci = t / 1156;
        int rem = t - ci * 1156;
        int rr = rem / 34, cc = rem - rr * 34;
        int gr = R0 + rr; if (gr > 127) gr = 127;
        int gc = C0 + cc; if (gc > 127) gc = 127;
        sh[ci][rr][cc] = in[(((size_t)b * 3 + ci) * 128 + gr) * 128 + gc];
    }
    __syncthreads();

    float acc[8][2][2] = {};
    int co0 = cg * 8;
#pragma unroll
    for (int ci = 0; ci < 3; ++ci) {
        float p[4][4];
#pragma unroll
        for (int r = 0; r < 4; ++r) {
            const float2* pr = reinterpret_cast<const float2*>(&sh[ci][2 * ty + r][2 * tx]);
            float2 a = pr[0], c2 = pr[1];
            p[r][0] = a.x; p[r][1] = a.y; p[r][2] = c2.x; p[r][3] = c2.y;
        }
#pragma unroll
        for (int j = 0; j < 8; ++j) {
            const float* wj = wt + ((size_t)(co0 + j) * 3 + ci) * 9;
#pragma unroll
            for (int kh = 0; kh < 3; ++kh)
#pragma unroll
                for (int kw = 0; kw < 3; ++kw) {
                    float wv = wj[kh * 3 + kw];
#pragma unroll
                    for (int dy = 0; dy < 2; ++dy)
#pragma unroll
                        for (int dx = 0; dx < 2; ++dx)
                            acc[j][dy][dx] = fmaf(wv, p[dy + kh][dx + kw], acc[j][dy][dx]);
                }
        }
    }
    int py = 16 * tr + ty, px = 16 * tc + tx;
    if (py < 63 && px < 63) {
#pragma unroll
        for (int j = 0; j < 8; ++j) {
            float v = fmaxf(fmaxf(acc[j][0][0], acc[j][0][1]),
                            fmaxf(acc[j][1][0], acc[j][1][1])) + bias[co0 + j];
            out[(((size_t)b * 64 + co0 + j) * 63 + py) * 63 + px] = fmaxf(v, 0.f);
        }
    }
}

// ===========================================================================
// conv2/conv3: LDS-staged, 8 co per thread, 1 pooled px per thread.
// ===========================================================================
template<int CIN, int HIN, int WIN, int PH, int PW, int COUT,
         int TH, int TW, int CI_BLK, int TILES_H, int TILES_W>
__global__ __launch_bounds__(256)
void conv_lds(const float* __restrict__ in, const float* __restrict__ wt,
              const float* __restrict__ bias, float* __restrict__ out)
{
    constexpr int RH = 2 * TH + 2;
    constexpr int CW = 2 * TW + 2;
    constexpr int CWp = (CW % 32 == 0) ? CW + 2 : CW;
    __shared__ float sh[CI_BLK][RH][CWp];

    int bx = blockIdx.x;
    constexpr int NTILES = TILES_H * TILES_W;
    int tile = bx % NTILES;
    int cg = (bx / NTILES) % (COUT / 8);
    int b  = bx / (NTILES * (COUT / 8));
    int thi = tile / TILES_W, twi = tile % TILES_W;
    int R0 = 2 * TH * thi, C0 = 2 * TW * twi;

    int tid = threadIdx.x;
    int ty = tid / TW, tx = tid - ty * TW;
    bool active = (tid < TH * TW);

    float acc[8][2][2] = {};
    int co0 = cg * 8;

    for (int ci0 = 0; ci0 < CIN; ci0 += CI_BLK) {
        __syncthreads();
        for (int t = tid; t < CI_BLK * RH * CW; t += 256) {
            int ci = t / (RH * CW);
            int rem = t - ci * (RH * CW);
            int rr = rem / CW, cc = rem - rr * CW;
            sh[ci][rr][cc] = in[(((size_t)b * CIN + ci0 + ci) * HIN + (R0 + rr)) * WIN + (C0 + cc)];
        }
        __syncthreads();
        if (active) {
#pragma unroll
            for (int ci = 0; ci < CI_BLK; ++ci) {
                float p[4][4];
#pragma unroll
                for (int r = 0; r < 4; ++r) {
                    const float2* pr = reinterpret_cast<const float2*>(&sh[ci][2 * ty + r][2 * tx]);
                    float2 a = pr[0], c2 = pr[1];
                    p[r][0] = a.x; p[r][1] = a.y; p[r][2] = c2.x; p[r][3] = c2.y;
                }
#pragma unroll
                for (int j = 0; j < 8; ++j) {
                    const float* wj = wt + ((size_t)(co0 + j) * CIN + (ci0 + ci)) * 9;
#pragma unroll
                    for (int kh = 0; kh < 3; ++kh)
#pragma unroll
                        for (int kw = 0; kw < 3; ++kw) {
                            float wv = wj[kh * 3 + kw];
#pragma unroll
                            for (int dy = 0; dy < 2; ++dy)
#pragma unroll
                                for (int dx = 0; dx < 2; ++dx)
                                    acc[j][dy][dx] = fmaf(wv, p[dy + kh][dx + kw], acc[j][dy][dx]);
                        }
                }
            }
        }
    }
    if (active) {
        int py = TH * thi + ty, px = TW * twi + tx;
        if (py < PH && px < PW) {
#pragma unroll
            for (int j = 0; j < 8; ++j) {
                float v = fmaxf(fmaxf(acc[j][0][0], acc[j][0][1]),
                                fmaxf(acc[j][1][0], acc[j][1][1])) + bias[co0 + j];
                out[(((size_t)b * COUT + co0 + j) * PH + py) * PW + px] = fmaxf(v, 0.f);
            }
        }
    }
}

// ===========================================================================
// conv4 v2: 256->512, 14x14 in, conv 12x12, pooled 6x6.
// Grid: (b, cg of 16 co) = 32x32 = 1024 blocks. 256 threads =
// (h = ci-half, co_local 0..15, sub 0..7: 3-row x 6-col conv tile).
// Each half accumulates 128 ci; halves merge in LDS, then pool from LDS.
// Padded strides verified conflict-free for the compute reads.
// ===========================================================================
__global__ __launch_bounds__(256)
void conv4_v2(const float* __restrict__ in, const float* __restrict__ wt,
              const float* __restrict__ bias, float* __restrict__ out)
{
    __shared__ float in_sh[2][8][14][18];   // [half][ci][row][col pad 18]
    __shared__ float w_sh[2][16][73];       // [half][co_local][ci*9+k pad 73]
    __shared__ float red[16][12][13];       // conv map [co][row][col pad 13]

    int bx = blockIdx.x;
    int cg = bx & 31;          // 32 groups of 16 co
    int b  = bx >> 5;
    int tid = threadIdx.x;
    int h  = tid >> 7;                 // ci half
    int r7 = tid & 127;
    int co_local = r7 >> 3;            // 0..15
    int sub = r7 & 7;                  // 0..7
    int rs = sub >> 1, cs = sub & 1;   // tile: rows 3*rs..+2, cols 6*cs..+5
    int R = 3 * rs, C = 6 * cs;

    float acc[3][6] = {};

    for (int k0 = 0; k0 < 128; k0 += 8) {
        __syncthreads();
        // stage input: 2 halves x 8 ci x 14 x 14
        for (int t = tid; t < 2 * 8 * 196; t += 256) {
            int hh = t >> 10;                 // t / 1568 ... careful: 8*196=1568
            int rem = t - hh * 1568;
            hh = t / 1568; rem = t - hh * 1568;
            int ci = rem / 196;
            int r2 = rem - ci * 196;
            int rr = r2 / 14, cc = r2 - rr * 14;
            in_sh[hh][ci][rr][cc] =
                in[(((size_t)b * 256 + hh * 128 + k0 + ci) * 14 + rr) * 14 + cc];
        }
        // stage weights: 2 halves x 16 co x 72
        for (int t = tid; t < 2 * 16 * 72; t += 256) {
            int hh = t / 1152;
            int rem = t - hh * 1152;
            int c = rem / 72, q = rem - c * 72;
            w_sh[hh][c][q] =
                wt[(size_t)(cg * 16 + c) * 2304 + (size_t)(hh * 128 + k0) * 9 + q];
        }
        __syncthreads();
#pragma unroll
        for (int ci = 0; ci < 8; ++ci) {
            float p[5][8];
#pragma unroll
            for (int r = 0; r < 5; ++r) {
                const float2* pr = reinterpret_cast<const float2*>(&in_sh[h][ci][R + r][C]);
                float2 a0 = pr[0], a1 = pr[1], a2 = pr[2], a3 = pr[3];
                p[r][0] = a0.x; p[r][1] = a0.y; p[r][2] = a1.x; p[r][3] = a1.y;
                p[r][4] = a2.x; p[r][5] = a2.y; p[r][6] = a3.x; p[r][7] = a3.y;
            }
#pragma unroll
            for (int kh = 0; kh < 3; ++kh)
#pragma unroll
                for (int kw = 0; kw < 3; ++kw) {
                    float wv = w_sh[h][co_local][ci * 9 + kh * 3 + kw];
#pragma unroll
                    for (int y = 0; y < 3; ++y)
#pragma unroll
                        for (int x = 0; x < 6; ++x)
                            acc[y][x] = fmaf(wv, p[y + kh][x + kw], acc[y][x]);
                }
        }
    }
    // merge halves in LDS
    __syncthreads();
    if (h == 0) {
#pragma unroll
        for (int y = 0; y < 3; ++y)
#pragma unroll
            for (int x = 0; x < 6; ++x)
                red[co_local][R + y][C + x] = acc[y][x];
    }
    __syncthreads();
    if (h == 1) {
#pragma unroll
        for (int y = 0; y < 3; ++y)
#pragma unroll
            for (int x = 0; x < 6; ++x)
                red[co_local][R + y][C + x] += acc[y][x];
    }
    __syncthreads();
    // pool + bias + relu: 16 co x 6 x 6 = 576 outputs
    for (int t = tid; t < 576; t += 256) {
        int co = t / 36;
        int rem = t - co * 36;
        int pr = rem / 6, pc = rem - pr * 6;
        float v = fmaxf(fmaxf(red[co][2 * pr][2 * pc],     red[co][2 * pr][2 * pc + 1]),
                        fmaxf(red[co][2 * pr + 1][2 * pc], red[co][2 * pr + 1][2 * pc + 1]));
        v += bias[cg * 16 + co];
        out[(((size_t)b * 512 + cg * 16 + co) * 6 + pr) * 6 + pc] = fmaxf(v, 0.f);
    }
}

// ---------------------------------------------------------------------------
// Y[b, o0 + j] = act( X[b,:] . W[o0+j,:] + bias[o0+j] ), j = 0,1 ; B = 32
// ---------------------------------------------------------------------------
__global__ __launch_bounds__(256)
void fc_two(const float* __restrict__ X, const float* __restrict__ W,
            const float* __restrict__ bias, float* __restrict__ Y,
            int K, int N, int act)
{
    int o0 = blockIdx.x * 2;
    int tid = threadIdx.x;
    const float* w0 = W + (size_t)o0 * K;
    const float* w1 = w0 + K;
    float a0[32], a1[32];
#pragma unroll
    for (int b = 0; b < 32; ++b) { a0[b] = 0.f; a1[b] = 0.f; }

    for (int k = tid; k < K; k += 256) {
        float wv0 = w0[k], wv1 = w1[k];
#pragma unroll
        for (int b = 0; b < 32; ++b) {
            float xv = X[(size_t)b * K + k];
            a0[b] = fmaf(wv0, xv, a0[b]);
            a1[b] = fmaf(wv1, xv, a1[b]);
        }
    }
    __shared__ float part[2][4][32];
    int lane = tid & 63, wv = tid >> 6;
#pragma unroll
    for (int b = 0; b < 32; ++b) {
        float s0 = a0[b], s1 = a1[b];
#pragma unroll
        for (int off = 32; off >= 1; off >>= 1) {
            s0 += __shfl_down(s0, off);
            s1 += __shfl_down(s1, off);
        }
        if (lane == 0) { part[0][wv][b] = s0; part[1][wv][b] = s1; }
    }
    __syncthreads();
    if (tid < 64) {
        int j = tid >> 5, b = tid & 31;
        float s = part[j][0][b] + part[j][1][b] + part[j][2][b] + part[j][3][b] + bias[o0 + j];
        if (act) s = tanhf(s);
        Y[(size_t)b * N + o0 + j] = s;
    }
}

// ---------------------------------------------------------------------------
// softmax over 10 logits -> ratio (output), then seg_limit rebalance
// ---------------------------------------------------------------------------
__global__ __launch_bounds__(64)
void post_kernel(const float* __restrict__ logits, float* __restrict__ ratio_out,
                 float* __restrict__ sl_out)
{
    int b = threadIdx.x;
    if (b >= 32) return;
    float lg[10];
#pragma unroll
    for (int j = 0; j < 10; ++j) lg[j] = logits[b * 10 + j];
    float mx = lg[0];
#pragma unroll
    for (int j = 1; j < 10; ++j) mx = fmaxf(mx, lg[j]);
    float e[10]; float ssum = 0.f;
#pragma unroll
    for (int j = 0; j < 10; ++j) { e[j] = expf(lg[j] - mx); ssum += e[j]; }
    float sl[10];
#pragma unroll
    for (int j = 0; j < 10; ++j) {
        float r = e[j] / ssum;
        ratio_out[b * 10 + j] = r;
        sl[j] = ceilf(r * 200.f);
    }
#pragma unroll
    for (int it = 0; it < 10; ++it) {
        float s = 0.f, mx2 = sl[0];
#pragma unroll
        for (int j = 0; j < 10; ++j) { s += sl[j]; mx2 = fmaxf(mx2, sl[j]); }
        float over = (s != 200.f) ? 1.f : 0.f;
        float reduced = 1.f;
#pragma unroll
        for (int j = 0; j < 10; ++j) {
            float mult = (sl[j] == mx2) ? 1.f : 0.f;
            sl[j] -= mult * reduced * over;
            reduced = fmaxf(reduced - mult, 0.f);
        }
    }
#pragma unroll
    for (int j = 0; j < 10; ++j) sl_out[b * 10 + j] = sl[j];
}

// ---------------------------------------------------------------------------
// trajectory assembly: grid 32 (batch), 256 threads (200 active points)
// ---------------------------------------------------------------------------
__global__ __launch_bounds__(256)
void traj_kernel(const float* __restrict__ base, const float* __restrict__ ipos,
                 const float* __restrict__ sm, float* __restrict__ out_traj,
                 float* __restrict__ out_starts)
{
    int b = blockIdx.x;
    int j = threadIdx.x;
    float bx0 = base[0], by0 = base[1];
    float bxL = base[398], byL = base[399];
    float bx = 0.f, by = 0.f;
    if (j < 200) { bx = base[2 * j]; by = base[2 * j + 1]; }
    float curx = ipos[b * 2 + 0], cury = ipos[b * 2 + 1];
    if (j == 0) { out_starts[b * 22 + 0] = curx; out_starts[b * 22 + 1] = cury; }
#pragma unroll
    for (int i = 0; i < 10; ++i) {
        float sx  = sm[b * 30 + i * 3 + 0];
        float sy  = sm[b * 30 + i * 3 + 1];
        float rot = tanhf(sm[b * 30 + i * 3 + 2]) * 3.14f;
        float c = cosf(rot), s = sinf(rot);
        float cx = bx0 * sx, cy = by0 * sy;
        if (j < 200) {
            float px = bx * sx, py = by * sy;
            float rx = c * (px - cx) - s * (py - cy) + cx;
            float ry = s * (px - cx) + c * (py - cy) + cy;
            size_t o = ((size_t)b * 2000 + i * 200 + j) * 2;
            out_traj[o + 0] = curx + rx;
            out_traj[o + 1] = cury + ry;
        }
        float pxL = bxL * sx, pyL = byL * sy;
        float exL = c * (pxL - cx) - s * (pyL - cy) + cx;
        float eyL = s * (pxL - cx) + c * (pyL - cy) + cy;
        curx += exL; cury += eyL;
        if (j == 0) {
            out_starts[b * 22 + (i + 1) * 2 + 0] = curx;
            out_starts[b * 22 + (i + 1) * 2 + 1] = cury;
        }
    }
}

// ---------------------------------------------------------------------------
// sampler: event-jump exact reimplementation of the reference scan.
// ---------------------------------------------------------------------------
__global__ __launch_bounds__(64)
void sample_kernel(const float* __restrict__ sl_in, const float* __restrict__ traj,
                   float* __restrict__ samp_out)
{
    __shared__ unsigned int maskb[32][63];
    __shared__ float ssl[32][10];
    int tid = threadIdx.x;
    for (int t = tid; t < 32 * 63; t += 64) ((unsigned int*)maskb)[t] = 0u;
    for (int t = tid; t < 32 * 10; t += 64) ((float*)ssl)[t] = sl_in[t];
    __syncthreads();
    if (tid >= 32) return;
    int b = tid;
    const float* tb = traj + (size_t)b * 4000;
    float* sp = samp_out + (size_t)b * 400;
    int out_n = 0;
    float last = 0.f, ntot = 0.f;
    float lim0 = ssl[b][0];
    float di = floorf(199.f / lim0);
    float ct0 = 0.f;
    if ((ntot < 200.f) && (ct0 < lim0) && (0.f - last == di)) {
        ntot += 1.f; ct0 += 1.f;
        maskb[b][0] |= 1u;
        sp[out_n * 2] = tb[0]; sp[out_n * 2 + 1] = tb[1]; ++out_n;
    }
    {
        float ndi = floorf((199.f - last) / (lim0 - ct0));
        if (di < ndi) di = ndi;
        if ((ntot < 200.f) && (ct0 < lim0) && (1.f - last == di)) {
            last = 1.f; ntot += 1.f; ct0 += 1.f;
            maskb[b][0] |= 2u;
            sp[out_n * 2] = tb[2]; sp[out_n * 2 + 1] = tb[3]; ++out_n;
        }
    }
    for (int seg = 0; seg < 10; ++seg) {
        float lim = ssl[b][seg];
        float ct = (seg == 0) ? ct0 : 0.f;
        float segbase = 200.f * seg;
        float segend = segbase + 199.f;
        float pos = (seg == 0) ? 2.f : segbase;
        float ndi = floorf((199.f - (last - segbase)) / (lim - ct));
        while ((ntot < 200.f) && (ct < lim)) {
            float fi = last + ndi;
            if (!(fi >= pos && fi <= segend)) break;
            int i = (int)fi;
            last = fi; ntot += 1.f; ct += 1.f;
            maskb[b][i >> 5] |= (1u << (i & 31));
            sp[out_n * 2] = tb[2 * i]; sp[out_n * 2 + 1] = tb[2 * i + 1]; ++out_n;
            pos = fi + 1.f;
            ndi = floorf((199.f - (last - segbase)) / (lim - ct));
        }
    }
    for (int i = 0; i < 2000 && out_n < 200; ++i) {
        if (!((maskb[b][i >> 5] >> (i & 31)) & 1u)) {
            sp[out_n * 2] = tb[2 * i]; sp[out_n * 2 + 1] = tb[2 * i + 1]; ++out_n;
        }
    }
}

// ---------------------------------------------------------------------------
extern "C" void kernel_launch(void* const* d_in, const int* in_sizes, int n_in,
                              void* d_out, int out_size, void* d_ws, size_t ws_size,
                              hipStream_t stream)
{
    const float* x    = (const float*)d_in[0];
    const float* w1   = (const float*)d_in[1];
    const float* b1   = (const float*)d_in[2];
    const float* w2   = (const float*)d_in[3];
    const float* b2   = (const float*)d_in[4];
    const float* w3   = (const float*)d_in[5];
    const float* b3   = (const float*)d_in[6];
    const float* w4   = (const float*)d_in[7];
    const float* b4   = (const float*)d_in[8];
    const float* fcw1 = (const float*)d_in[9];
    const float* fcb1 = (const float*)d_in[10];
    const float* fcw2 = (const float*)d_in[11];
    const float* fcb2 = (const float*)d_in[12];
    const float* wi   = (const float*)d_in[13];
    const float* bi   = (const float*)d_in[14];
    const float* wsw  = (const float*)d_in[15];
    const float* bs   = (const float*)d_in[16];
    const float* wr   = (const float*)d_in[17];
    const float* br   = (const float*)d_in[18];
    const float* base = (const float*)d_in[19];

    float* out = (float*)d_out;
    float* ws  = (float*)d_ws;

    float* p1   = ws + 0;        // 32x64x63x63   (8,128,512)
    float* p2   = ws + 8128512;  // 32x128x30x30  (3,686,400)
    float* p3   = ws + 0;        // 32x256x14x14  (reuses p1)
    float* feat = ws + 8128512;  // 32x512x6x6    (reuses p2)
    float* z1   = ws + 0;        // 32x2048       (reuses p3)
    float* z2   = ws + 65536;    // 32x2048
    float* ipos = ws + 131072;   // 32x2
    float* smod = ws + 131136;   // 32x30
    float* rlog = ws + 132096;   // 32x10
    float* slim = ws + 132416;   // 32x10

    float* out_samp   = out;            // 32*200*2 = 12800
    float* out_starts = out + 12800;    // 32*11*2  = 704
    float* out_ratio  = out + 13504;    // 32*10    = 320
    float* out_traj   = out + 13824;    // 32*2000*2 = 128000

    conv1_lds<<<4096, 256, 0, stream>>>(x, w1, b1, p1);
    conv_lds<64, 63, 63, 30, 30, 128, 15, 15, 4, 2, 2>
        <<<2048, 256, 0, stream>>>(p1, w2, b2, p2);
    conv_lds<128, 30, 30, 14, 14, 256, 14, 14, 4, 1, 1>
        <<<1024, 256, 0, stream>>>(p2, w3, b3, p3);
    conv4_v2<<<1024, 256, 0, stream>>>(p3, w4, b4, feat);

    fc_two<<<1024, 256, 0, stream>>>(feat, fcw1, fcb1, z1, 18432, 2048, 1);
    fc_two<<<1024, 256, 0, stream>>>(z1, fcw2, fcb2, z2, 2048, 2048, 0);

    fc_two<<<1, 256, 0, stream>>>(z2, wi, bi, ipos, 2048, 2, 0);
    fc_two<<<15, 256, 0, stream>>>(z2, wsw, bs, smod, 2048, 30, 0);
    fc_two<<<5, 256, 0, stream>>>(z2, wr, br, rlog, 2048, 10, 0);

    post_kernel<<<1, 64, 0, stream>>>(rlog, out_ratio, slim);
    traj_kernel<<<32, 256, 0, stream>>>(base, ipos, smod, out_traj, out_starts);
    sample_kernel<<<1, 64, 0, stream>>>(slim, out_traj, out_samp);
}